// Round 10
// baseline (647.963 us; speedup 1.0000x reference)
//
#include <hip/hip_runtime.h>

// Problem constants (match reference)
constexpr int B_  = 2;
constexpr int L_  = 1024;
constexpr int D_  = 768;
constexpr int E_  = 1536;
constexpr int N_  = 16;
constexpr int R_  = 48;
constexpr int NL_ = 4;
constexpr int NC_ = 5;
constexpr int M_  = B_ * L_;        // 2048 token rows
constexpr int E2_ = 2 * E_;         // 3072
constexpr int XD_ = R_ + 2 * N_;    // 80
constexpr float EPS_ = 1e-5f;
constexpr float LOG2E_ = 1.4426950408889634f;

constexpr int NCH_ = 16;            // time-chunks for parallel scan
constexpr int CL_  = L_ / NCH_;     // 64 timesteps per chunk
constexpr int KS_  = 8;             // split-K factor for xproj GEMM
constexpr int PC_  = 64;            // t-chunks for final pool (128 blocks)

typedef __attribute__((ext_vector_type(8))) short bf16x8;
typedef __attribute__((ext_vector_type(4))) float f32x4;
typedef const __attribute__((address_space(1))) void* gas_t;
typedef __attribute__((address_space(3))) void* las_t;

__device__ __forceinline__ float exp2fast(float x) { return __builtin_amdgcn_exp2f(x); }
__device__ __forceinline__ float sigm(float x) { return 1.0f / (1.0f + __expf(-x)); }
__device__ __forceinline__ float softplusf(float x) { return x > 20.0f ? x : log1pf(__expf(x)); }
__device__ __forceinline__ ushort f2b(float f) {  // fp32 -> bf16 RNE
  union { float f; unsigned u; } v; v.f = f;
  unsigned r = (v.u + 0x7fffu + ((v.u >> 16) & 1u)) >> 16;
  return (ushort)r;
}
__device__ __forceinline__ float b2f(ushort u) {
  union { unsigned u; float f; } v; v.u = ((unsigned)u) << 16;
  return v.f;
}
__device__ __forceinline__ float b2f_lo(unsigned p) {
  union { unsigned u; float f; } v; v.u = p << 16;
  return v.f;
}
__device__ __forceinline__ float b2f_hi(unsigned p) {
  union { unsigned u; float f; } v; v.u = p & 0xffff0000u;
  return v.f;
}

// DPP row_ror add: sum over 16-lane rows, full-rate VALU
template <int CTRL>
__device__ __forceinline__ float dpp_add(float x) {
  int yi = __builtin_amdgcn_update_dpp(0, __builtin_bit_cast(int, x), CTRL, 0xf, 0xf, false);
  return x + __builtin_bit_cast(float, yi);
}
__device__ __forceinline__ float row_sum16(float x) {
  x = dpp_add<0x121>(x);
  x = dpp_add<0x122>(x);
  x = dpp_add<0x124>(x);
  x = dpp_add<0x128>(x);
  return x;
}

__device__ __forceinline__ float block_sum(float v, float* sm) {
  #pragma unroll
  for (int o = 32; o > 0; o >>= 1) v += __shfl_xor(v, o);
  if ((threadIdx.x & 63) == 0) sm[threadIdx.x >> 6] = v;
  __syncthreads();
  return sm[0] + sm[1] + sm[2] + sm[3];
}

// One-shot prep: weight f2b conversions (in_w folded with norm_w, out_w, xproj_w;
// dt_w padded 48->64) PLUS the input projection h = x @ proj_w^T + proj_b
// (emits h fp32, h bf16, and atomic row-sumsq into ssq; ssq pre-zeroed by memset).
constexpr int WS1_ = NL_ * E2_ * D_;
constexpr int WS2_ = NL_ * D_ * E_;
constexpr int WS3_ = NL_ * XD_ * E_;
constexpr int WS4_ = NL_ * E_ * 64;
constexpr int WTOT_ = WS1_ + WS2_ + WS3_ + WS4_;
constexpr int WB_ = WTOT_ / 4 / 256;            // weight-conv blocks (exact: 14688)
__global__ __launch_bounds__(256) void k_wprep(const float* __restrict__ in_w, const float* __restrict__ out_w,
                                               const float* __restrict__ xw, const float* __restrict__ dw,
                                               const float* __restrict__ nw,
                                               ushort* __restrict__ in_wb, ushort* __restrict__ out_wb,
                                               ushort* __restrict__ xwb, ushort* __restrict__ dtwb,
                                               const float* __restrict__ x, const float* __restrict__ pw,
                                               const float* __restrict__ pb, float* __restrict__ h,
                                               ushort* __restrict__ hb, float* __restrict__ ssq) {
  if (blockIdx.x >= WB_) {
    // input projection: 3 blocks per token row
    __shared__ float xs[12];
    __shared__ float sm[4];
    int bx = blockIdx.x - WB_;
    int m = bx / 3;
    int d = (bx % 3) * 256 + threadIdx.x;
    if (threadIdx.x < 12) xs[threadIdx.x] = x[m * 12 + threadIdx.x];
    __syncthreads();
    float acc = pb[d];
    #pragma unroll
    for (int j = 0; j < 12; j++) acc = fmaf(xs[j], pw[d * 12 + j], acc);
    h[(size_t)m * D_ + d] = acc;
    hb[(size_t)m * D_ + d] = f2b(acc);
    float s = block_sum(acc * acc, sm);
    if (threadIdx.x == 0) atomicAdd(&ssq[m], s);
    return;
  }
  int i = (blockIdx.x * 256 + threadIdx.x) * 4;
  if (i < WS1_) {
    float4 v = *(const float4*)(in_w + i);
    int l = i / (E2_ * D_);
    int d = i % D_;                      // 4 consecutive d in the same row (D%4==0)
    float4 w = *(const float4*)(nw + l * D_ + d);
    *(ushort4*)(in_wb + i) = make_ushort4(f2b(v.x * w.x), f2b(v.y * w.y), f2b(v.z * w.z), f2b(v.w * w.w));
  } else if (i < WS1_ + WS2_) {
    int j = i - WS1_;
    float4 v = *(const float4*)(out_w + j);
    *(ushort4*)(out_wb + j) = make_ushort4(f2b(v.x), f2b(v.y), f2b(v.z), f2b(v.w));
  } else if (i < WS1_ + WS2_ + WS3_) {
    int j = i - WS1_ - WS2_;
    float4 v = *(const float4*)(xw + j);
    *(ushort4*)(xwb + j) = make_ushort4(f2b(v.x), f2b(v.y), f2b(v.z), f2b(v.w));
  } else {
    int j = i - WS1_ - WS2_ - WS3_;
    int k = j & 63, e = j >> 6;
    ushort4 o;
    o.x = (k + 0 < R_) ? f2b(dw[e * R_ + k + 0]) : (ushort)0;
    o.y = (k + 1 < R_) ? f2b(dw[e * R_ + k + 1]) : (ushort)0;
    o.z = (k + 2 < R_) ? f2b(dw[e * R_ + k + 2]) : (ushort)0;
    o.w = (k + 3 < R_) ? f2b(dw[e * R_ + k + 3]) : (ushort)0;
    *(ushort4*)(dtwb + j) = o;
  }
}

// C[M,Nd] = A_bf16[M,Kd] @ Bw_bf16[Nd,Kd]^T. MFMA 16x16x32 bf16.
// MODE 4: bf16 C=v*rsqrt(res[row]/D+eps)   (fused rmsnorm scale; res=ssq)
// MODE 5: fp32 C=v+res[off], also bf16 copy to Cb and atomic row-sumsq into ssq
template <int BM, int BN, int MODE>
__global__ __launch_bounds__(256) void k_gemm_bf(const ushort* __restrict__ A, const ushort* __restrict__ Bw,
                                                 void* __restrict__ Cv, const float* __restrict__ res,
                                                 ushort* __restrict__ Cb, float* __restrict__ ssq,
                                                 int Kd, int Nd) {
  constexpr int AM = BM / 32, BNF = BN / 32;
  __shared__ ushort sA[BM * 32];
  __shared__ ushort sB[BN * 32];
  const int tid = threadIdx.x;
  const int wave = tid >> 6, lane = tid & 63;
  const int q = lane >> 4, r = lane & 15;
  const int wm = wave >> 1, wn = wave & 1;
  const int m0 = blockIdx.y * BM, n0 = blockIdx.x * BN;
  f32x4 acc[AM][BNF] = {};

  for (int k0 = 0; k0 < Kd; k0 += 32) {
    #pragma unroll
    for (int j = 0; j < BM / 64; j++) {
      int i = j * 256 + tid;
      const ushort* gp = A + (size_t)(m0 + (i >> 2)) * Kd + k0 + ((i & 3) << 3);
      __builtin_amdgcn_global_load_lds((gas_t)gp, (las_t)(sA + ((j * 256 + wave * 64) << 3)), 16, 0, 0);
    }
    #pragma unroll
    for (int j = 0; j < BN / 64; j++) {
      int i = j * 256 + tid;
      const ushort* gp = Bw + (size_t)(n0 + (i >> 2)) * Kd + k0 + ((i & 3) << 3);
      __builtin_amdgcn_global_load_lds((gas_t)gp, (las_t)(sB + ((j * 256 + wave * 64) << 3)), 16, 0, 0);
    }
    __syncthreads();
    bf16x8 af[AM], bfv[BNF];
    #pragma unroll
    for (int mi = 0; mi < AM; mi++)
      af[mi] = *(const bf16x8*)&sA[(wm * (BM / 2) + mi * 16 + r) * 32 + q * 8];
    #pragma unroll
    for (int nj = 0; nj < BNF; nj++)
      bfv[nj] = *(const bf16x8*)&sB[(wn * (BN / 2) + nj * 16 + r) * 32 + q * 8];
    #pragma unroll
    for (int mi = 0; mi < AM; mi++)
      #pragma unroll
      for (int nj = 0; nj < BNF; nj++)
        acc[mi][nj] = __builtin_amdgcn_mfma_f32_16x16x32_bf16(af[mi], bfv[nj], acc[mi][nj], 0, 0, 0);
    __syncthreads();
  }
  // C/D layout: col = lane&15, row = (lane>>4)*4 + reg
  #pragma unroll
  for (int mi = 0; mi < AM; mi++) {
    #pragma unroll
    for (int rg = 0; rg < 4; rg++) {
      int row = m0 + wm * (BM / 2) + mi * 16 + q * 4 + rg;
      float rs = 0.0f, ssl = 0.0f;
      if (MODE == 4) rs = rsqrtf(res[row] * (1.0f / D_) + EPS_);
      #pragma unroll
      for (int nj = 0; nj < BNF; nj++) {
        int col = n0 + wn * (BN / 2) + nj * 16 + r;
        size_t off = (size_t)row * Nd + col;
        float v = acc[mi][nj][rg];
        if (MODE == 4) {
          ((ushort*)Cv)[off] = f2b(v * rs);
        } else if (MODE == 5) {
          v += res[off];
          ((float*)Cv)[off] = v;
          Cb[off] = f2b(v);
          ssl = fmaf(v, v, ssl);
        }
      }
      if (MODE == 5) {
        float sr = row_sum16(ssl);      // 16-lane group = fixed q = one row
        if (r == 0) atomicAdd(&ssq[row], sr);
      }
    }
  }
}

// xproj GEMM, split-K: part[ks][M][80] = u_bf[M, ks-slice] @ xwb[80, ks-slice]^T
__global__ __launch_bounds__(256) void k_gemm_x(const ushort* __restrict__ A, const ushort* __restrict__ Bw,
                                                float* __restrict__ part) {
  __shared__ ushort sA[64 * 32];
  __shared__ ushort sB[80 * 32];
  const int tid = threadIdx.x;
  const int wave = tid >> 6, lane = tid & 63;
  const int q = lane >> 4, r = lane & 15;
  const int m0 = blockIdx.x * 64;
  const int kbeg = blockIdx.y * (E_ / KS_), kend = kbeg + E_ / KS_;
  f32x4 acc[5] = {};

  for (int k0 = kbeg; k0 < kend; k0 += 32) {
    {
      const ushort* gp = A + (size_t)(m0 + wave * 16 + (lane >> 2)) * E_ + k0 + ((lane & 3) << 3);
      __builtin_amdgcn_global_load_lds((gas_t)gp, (las_t)(sA + (wave << 9)), 16, 0, 0);
    }
    #pragma unroll
    for (int j = wave; j < 5; j += 4) {
      const ushort* gp = Bw + (size_t)(j * 16 + (lane >> 2)) * E_ + k0 + ((lane & 3) << 3);
      __builtin_amdgcn_global_load_lds((gas_t)gp, (las_t)(sB + (j << 9)), 16, 0, 0);
    }
    __syncthreads();
    bf16x8 af = *(const bf16x8*)&sA[(wave * 16 + r) * 32 + q * 8];
    #pragma unroll
    for (int nj = 0; nj < 5; nj++) {
      bf16x8 bfv = *(const bf16x8*)&sB[(nj * 16 + r) * 32 + q * 8];
      acc[nj] = __builtin_amdgcn_mfma_f32_16x16x32_bf16(af, bfv, acc[nj], 0, 0, 0);
    }
    __syncthreads();
  }
  float* pp = part + (size_t)blockIdx.y * M_ * XD_;
  #pragma unroll
  for (int nj = 0; nj < 5; nj++) {
    int col = nj * 16 + r;
    #pragma unroll
    for (int rg = 0; rg < 4; rg++) {
      int row = m0 + wave * 16 + q * 4 + rg;
      pp[(size_t)row * XD_ + col] = acc[nj][rg];
    }
  }
}

// combine split-K partials -> xdbc fp32 [M][80] + bf16 dt-input copy [M][64]
// ALSO zeroes ssq[m] ahead of this layer's gemm_out MODE-5 accumulation.
__global__ __launch_bounds__(256) void k_xfin(const float* __restrict__ part, float* __restrict__ xdbc,
                                              ushort* __restrict__ xb, float* __restrict__ ssq) {
  int i = blockIdx.x * 256 + threadIdx.x;   // over M*80
  if (i < M_) ssq[i] = 0.0f;
  int m = i / XD_, col = i - m * XD_;
  float s = 0.0f;
  #pragma unroll
  for (int ks = 0; ks < KS_; ks++) s += part[(size_t)ks * M_ * XD_ + i];
  xdbc[i] = s;
  if (col < R_) xb[(size_t)m * 64 + col] = f2b(s);
  else if (col < 64) xb[(size_t)m * 64 + col] = 0;
}

// conv + silu for u; silu for gate. bf16 in (proj_bf), bf16 out.
constexpr int TC_ = 4;
__global__ __launch_bounds__(384) void k_conv2(const ushort* __restrict__ proj, const float* __restrict__ cw,
                                               const float* __restrict__ cb, ushort* __restrict__ ub16,
                                               ushort* __restrict__ gb16) {
  int m0 = blockIdx.x * TC_;          // TC_ | L_, so one batch per block
  int t0 = m0 & (L_ - 1);
  int base = m0 - t0;                 // b*L
  int e4 = threadIdx.x * 4;
  float wv[4][4];
  #pragma unroll
  for (int j = 0; j < 4; j++) {
    float4 w = *(const float4*)(cw + (e4 + j) * 4);
    wv[j][0] = w.x; wv[j][1] = w.y; wv[j][2] = w.z; wv[j][3] = w.w;
  }
  float4 bb = *(const float4*)(cb + e4);
  float bbv[4] = {bb.x, bb.y, bb.z, bb.w};
  float win[4][4];                    // win[0..2] = rows t-3..t-1; win[3] = current
  #pragma unroll
  for (int s = 0; s < 3; s++) {
    int t = t0 - 3 + s;
    if (t >= 0) {
      uint2 p = *(const uint2*)(proj + (size_t)(base + t) * E2_ + e4);
      win[s][0] = b2f_lo(p.x); win[s][1] = b2f_hi(p.x);
      win[s][2] = b2f_lo(p.y); win[s][3] = b2f_hi(p.y);
    } else {
      win[s][0] = win[s][1] = win[s][2] = win[s][3] = 0.0f;
    }
  }
  #pragma unroll
  for (int j = 0; j < TC_; j++) {
    size_t m = (size_t)(m0 + j);
    uint2 p = *(const uint2*)(proj + m * E2_ + e4);
    win[3][0] = b2f_lo(p.x); win[3][1] = b2f_hi(p.x);
    win[3][2] = b2f_lo(p.y); win[3][3] = b2f_hi(p.y);
    float o[4];
    #pragma unroll
    for (int c = 0; c < 4; c++) {
      float a = bbv[c];
      a = fmaf(wv[c][0], win[0][c], a);
      a = fmaf(wv[c][1], win[1][c], a);
      a = fmaf(wv[c][2], win[2][c], a);
      a = fmaf(wv[c][3], win[3][c], a);
      o[c] = a * sigm(a);
    }
    uint2 uo;
    uo.x = (unsigned)f2b(o[0]) | ((unsigned)f2b(o[1]) << 16);
    uo.y = (unsigned)f2b(o[2]) | ((unsigned)f2b(o[3]) << 16);
    *(uint2*)(ub16 + m * E_ + e4) = uo;
    #pragma unroll
    for (int s = 0; s < 3; s++) {
      win[s][0] = win[s + 1][0]; win[s][1] = win[s + 1][1];
      win[s][2] = win[s + 1][2]; win[s][3] = win[s + 1][3];
    }
  }
  // gate -> silu -> bf16 (no overlap; read once)
  #pragma unroll
  for (int j = 0; j < TC_; j++) {
    size_t m = (size_t)(m0 + j);
    uint2 g = *(const uint2*)(proj + m * E2_ + E_ + e4);
    float g0 = b2f_lo(g.x), g1 = b2f_hi(g.x), g2 = b2f_lo(g.y), g3 = b2f_hi(g.y);
    g0 *= sigm(g0); g1 *= sigm(g1); g2 *= sigm(g2); g3 *= sigm(g3);
    uint2 go;
    go.x = (unsigned)f2b(g0) | ((unsigned)f2b(g1) << 16);
    go.y = (unsigned)f2b(g2) | ((unsigned)f2b(g3) << 16);
    *(uint2*)(gb16 + m * E_ + e4) = go;
  }
}

// ---- Parallel (chunked) selective scan; dt via MFMA; transposed LDS ---------
// Time-major per-channel layouts (rows padded +2): one ds_read_b128 fetches TWO
// timesteps of (dt, dtu) or (B, C) -> 1 DS issue/t and conflict-free banking.
// Math order identical to round 9 (bit-identical output).
__global__ __launch_bounds__(256, 8) void k_scanA(const ushort* __restrict__ u, const ushort* __restrict__ xb,
                                                  const ushort* __restrict__ dtw, const float* __restrict__ dtb_p,
                                                  const float* __restrict__ xdbc, const float* __restrict__ A_log,
                                                  float* __restrict__ Pst, float* __restrict__ Sst) {
  __shared__ __align__(16) float2 s_ddT[16][CL_ + 2];  // (dt, dt*u) per channel, 8.25 KB
  __shared__ __align__(16) float  s_bT [16][CL_ + 2];  // B per n, 4.1 KB
  const int tid = threadIdx.x;
  const int e0 = blockIdx.x << 4;
  const int b  = blockIdx.y;
  const int c  = blockIdx.z;
  const int n  = tid & 15, el = tid >> 4;
  const int e  = e0 + el;
  const int wave = tid >> 6, lane = tid & 63;
  const int q = lane >> 4, r = lane & 15;
  const float A2 = -__expf(A_log[e * N_ + n]) * LOG2E_;
  const int mb = b * L_ + c * CL_;

  // dt tile via MFMA: wave w owns t-range [w*16, w*16+16)
  f32x4 dacc = {};
  #pragma unroll
  for (int k0 = 0; k0 < 64; k0 += 32) {
    bf16x8 af = *(const bf16x8*)&xb[(size_t)(mb + wave * 16 + r) * 64 + k0 + q * 8];
    bf16x8 bfv = *(const bf16x8*)&dtw[(e0 + r) * 64 + k0 + q * 8];
    dacc = __builtin_amdgcn_mfma_f32_16x16x32_bf16(af, bfv, dacc, 0, 0, 0);
  }
  {
    float db = dtb_p[e0 + r];
    #pragma unroll
    for (int rg = 0; rg < 4; rg++)
      s_ddT[r][wave * 16 + q * 4 + rg].x = softplusf(dacc[rg] + db);
  }

  ushort r_u[4];
  #pragma unroll
  for (int j = 0; j < 4; j++) {
    r_u[j] = u[(size_t)(mb + j * 16 + el) * E_ + e0 + n];
    int idx = j * 256 + tid;
    s_bT[idx & 15][idx >> 4] = xdbc[(size_t)(mb + (idx >> 4)) * XD_ + R_ + (idx & 15)];
  }
  __syncthreads();
  // dtu pass: channel n, t = j*16+el
  #pragma unroll
  for (int j = 0; j < 4; j++) {
    int t = j * 16 + el;
    s_ddT[n][t].y = s_ddT[n][t].x * b2f(r_u[j]);
  }
  __syncthreads();

  float hs = 0.0f, sdt = 0.0f;
  #pragma unroll 8
  for (int t = 0; t < CL_; t += 2) {
    float4 dd = *(const float4*)&s_ddT[el][t];
    float2 bb = *(const float2*)&s_bT[n][t];
    float dA0 = exp2fast(dd.x * A2);
    hs = fmaf(hs, dA0, dd.y * bb.x);
    sdt += dd.x;
    float dA1 = exp2fast(dd.z * A2);
    hs = fmaf(hs, dA1, dd.w * bb.y);
    sdt += dd.z;
  }
  size_t o = (((size_t)(b * NCH_ + c) * E_) + e) * N_ + n;
  Pst[o] = exp2fast(A2 * sdt);
  Sst[o] = hs;
}

// scanC: transposed LDS + batched y-finalize (lane n captures t==base+n).
__global__ __launch_bounds__(256, 6) void k_scanC(const ushort* __restrict__ u, const ushort* __restrict__ xb,
                                                  const ushort* __restrict__ dtw, const float* __restrict__ dtb_p,
                                                  const float* __restrict__ xdbc, const ushort* __restrict__ gb,
                                                  const float* __restrict__ A_log, const float* __restrict__ Dp,
                                                  const float* __restrict__ Pst, const float* __restrict__ Sst,
                                                  ushort* __restrict__ y) {
  __shared__ __align__(16) float2 s_ddT[16][CL_ + 2]; // (dt, dt*u) per channel, 8.25 KB
  __shared__ __align__(16) float2 s_bcT[16][CL_ + 2]; // (B, C) per n, 8.25 KB
  __shared__ uint   s_ug[CL_][16];                    // 4 KB: u | g<<16
  __shared__ ushort s_y [CL_][20];                    // 2.5 KB (padded rows)
  const int tid = threadIdx.x;
  const int e0 = blockIdx.x << 4;
  const int b  = blockIdx.y;
  const int c  = blockIdx.z;
  const int n  = tid & 15, el = tid >> 4;
  const int e  = e0 + el;
  const int wave = tid >> 6, lane = tid & 63;
  const int q = lane >> 4, r = lane & 15;
  const float A2 = -__expf(A_log[e * N_ + n]) * LOG2E_;
  const float Dv = Dp[e];
  const int t0 = c * CL_;
  const int mb = b * L_ + t0;

  // dt tile via MFMA (identical to k_scanA)
  f32x4 dacc = {};
  #pragma unroll
  for (int k0 = 0; k0 < 64; k0 += 32) {
    bf16x8 af = *(const bf16x8*)&xb[(size_t)(mb + wave * 16 + r) * 64 + k0 + q * 8];
    bf16x8 bfv = *(const bf16x8*)&dtw[(e0 + r) * 64 + k0 + q * 8];
    dacc = __builtin_amdgcn_mfma_f32_16x16x32_bf16(af, bfv, dacc, 0, 0, 0);
  }
  {
    float db = dtb_p[e0 + r];
    #pragma unroll
    for (int rg = 0; rg < 4; rg++)
      s_ddT[r][wave * 16 + q * 4 + rg].x = softplusf(dacc[rg] + db);
  }

  ushort r_u[4], r_g[4];
  float r_bc[8];
  #pragma unroll
  for (int j = 0; j < 4; j++) {
    size_t m = (size_t)(mb + j * 16 + el);
    r_u[j] = u[m * E_ + e0 + n];
    r_g[j] = gb[m * E_ + e0 + n];
  }
  #pragma unroll
  for (int j = 0; j < 8; j++) {
    int idx = j * 256 + tid;
    r_bc[j] = xdbc[(size_t)(mb + (idx >> 5)) * XD_ + R_ + (idx & 31)];
  }

  // branchless parallel lookback over predecessor chunk summaries
  float hs = 0.0f;
  if (c > 0) {
    float pv[NCH_ - 1], sv[NCH_ - 1];
    #pragma unroll
    for (int cc = 0; cc < NCH_ - 1; cc++) {
      int ci = cc < c ? cc : c - 1;
      size_t o = (((size_t)(b * NCH_ + ci) * E_) + e) * N_ + n;
      pv[cc] = Pst[o];
      sv[cc] = Sst[o];
    }
    #pragma unroll
    for (int cc = 0; cc < NCH_ - 1; cc++) {
      bool v = cc < c;
      hs = fmaf(v ? pv[cc] : 1.0f, hs, v ? sv[cc] : 0.0f);
    }
  }

  #pragma unroll
  for (int j = 0; j < 4; j++) {
    int t = j * 16 + el;
    s_ug[t][n] = (uint)r_u[j] | ((uint)r_g[j] << 16);
  }
  #pragma unroll
  for (int j = 0; j < 8; j++) {
    int idx = j * 256 + tid;
    int t = idx >> 5, col = idx & 31;
    ((float*)&s_bcT[col & 15][0])[2 * t + (col >> 4)] = r_bc[j];
  }
  __syncthreads();
  // dtu pass: channel n, t = j*16+el
  #pragma unroll
  for (int j = 0; j < 4; j++) {
    int t = j * 16 + el;
    s_ddT[n][t].y = s_ddT[n][t].x * b2f(r_u[j]);
  }
  __syncthreads();

  for (int base = 0; base < CL_; base += 16) {
    float pslot = 0.0f;
    #pragma unroll
    for (int tt = 0; tt < 16; tt += 2) {
      int t = base + tt;
      float4 dd = *(const float4*)&s_ddT[el][t];
      float4 bc = *(const float4*)&s_bcT[n][t];
      float dA0 = exp2fast(dd.x * A2);
      hs = fmaf(hs, dA0, dd.y * bc.x);
      float p0 = row_sum16(hs * bc.y);
      pslot = (n == tt) ? p0 : pslot;
      float dA1 = exp2fast(dd.z * A2);
      hs = fmaf(hs, dA1, dd.w * bc.z);
      float p1 = row_sum16(hs * bc.w);
      pslot = (n == tt + 1) ? p1 : pslot;
    }
    // all-lane flush: lane n finalizes y at t = base+n
    uint ug = s_ug[base + n][el];
    s_y[base + n][el] = f2b((pslot + b2f_lo(ug) * Dv) * b2f_hi(ug));
  }
  __syncthreads();

  {
    int row = tid >> 2, seg = tid & 3;
    uint2 v = *(const uint2*)&s_y[row][seg * 4];
    *(uint2*)(y + (size_t)(mb + row) * E_ + e0 + seg * 4) = v;
  }
}

// Fused rowscale+pool: block (pc,b) reads its 16 rows ONCE; per row block-reduce
// sumsq -> rs, accumulate h*rs in registers; write one 768-float partial.
__global__ __launch_bounds__(256) void k_pool(const float* __restrict__ h, float* __restrict__ pooledP) {
  __shared__ float sm[4];
  const int pc = blockIdx.x, b = blockIdx.y;
  const int tid = threadIdx.x;
  const int t0 = pc * (L_ / PC_);
  float a0 = 0.0f, a1 = 0.0f, a2 = 0.0f;
  for (int rowi = 0; rowi < L_ / PC_; rowi++) {
    const float* hr = h + (size_t)(b * L_ + t0 + rowi) * D_;
    float v0 = hr[tid], v1 = hr[tid + 256], v2 = hr[tid + 512];
    float s = block_sum(v0 * v0 + v1 * v1 + v2 * v2, sm);
    float rs = rsqrtf(s * (1.0f / D_) + EPS_);
    a0 = fmaf(v0, rs, a0); a1 = fmaf(v1, rs, a1); a2 = fmaf(v2, rs, a2);
    __syncthreads();   // guard sm reuse next row
  }
  float* pp = pooledP + ((size_t)pc * B_ + b) * D_;
  pp[tid] = a0; pp[tid + 256] = a1; pp[tid + 512] = a2;
}

// out[b,c]: cooperative LDS reduce of pooledP (coalesced), then wave-dot from LDS.
__global__ __launch_bounds__(256) void k_logits(const float* __restrict__ pooledP, const float* __restrict__ fw,
                                                const float* __restrict__ cw, const float* __restrict__ cb,
                                                float* __restrict__ out) {
  __shared__ float sp[B_ * D_];   // 6 KB
  int tid = threadIdx.x;
  for (int d = tid; d < B_ * D_; d += 256) {
    int b = d / D_, dd = d - b * D_;
    float pd = 0.0f;
    #pragma unroll 8
    for (int pc = 0; pc < PC_; pc++) pd += pooledP[((size_t)pc * B_ + b) * D_ + dd];
    sp[d] = pd * fw[dd] * (1.0f / L_);
  }
  __syncthreads();
  int wv = tid >> 6, ln = tid & 63;
  for (int p = wv; p < B_ * NC_; p += 4) {
    int b = p / NC_, c = p % NC_;
    float s = 0.0f;
    for (int d = ln; d < D_; d += 64) s = fmaf(sp[b * D_ + d], cw[c * D_ + d], s);
    #pragma unroll
    for (int o = 32; o > 0; o >>= 1) s += __shfl_xor(s, o);
    if (ln == 0) out[p] = s + cb[c];
  }
}

extern "C" void kernel_launch(void* const* d_in, const int* in_sizes, int n_in,
                              void* d_out, int out_size, void* d_ws, size_t ws_size,
                              hipStream_t stream) {
  const float* x       = (const float*)d_in[0];
  const float* proj_w  = (const float*)d_in[1];
  const float* proj_b  = (const float*)d_in[2];
  const float* norm_w  = (const float*)d_in[3];
  const float* in_w    = (const float*)d_in[4];
  const float* conv_w  = (const float*)d_in[5];
  const float* conv_b  = (const float*)d_in[6];
  const float* xproj_w = (const float*)d_in[7];
  const float* dt_w    = (const float*)d_in[8];
  const float* dt_b    = (const float*)d_in[9];
  const float* A_log   = (const float*)d_in[10];
  const float* D_param = (const float*)d_in[11];
  const float* out_w   = (const float*)d_in[12];
  const float* fnorm_w = (const float*)d_in[13];
  const float* cls_w   = (const float*)d_in[14];
  const float* cls_b   = (const float*)d_in[15];
  float* out = (float*)d_out;

  // workspace layout (floats)
  float* h      = (float*)d_ws;                         // M*D
  float* xdbc   = h + (size_t)M_ * D_;                  // M*80
  float* ssq    = xdbc + (size_t)M_ * XD_;              // M (running row sumsq)
  float* pooledP = ssq + M_;                            // PC*B*D
  float* Pst    = pooledP + (size_t)PC_ * B_ * D_;      // B*NCH*E*N
  float* Sst    = Pst + (size_t)B_ * NCH_ * E_ * N_;    // B*NCH*E*N
  float* xpart  = Sst + (size_t)B_ * NCH_ * E_ * N_;    // KS*M*80
  ushort* proj_bf = (ushort*)(xpart + (size_t)KS_ * M_ * XD_);  // M*2E bf16
  ushort* hb_bf   = proj_bf + (size_t)M_ * E2_;         // M*D (bf16 of residual h)
  ushort* y_bf    = hb_bf + (size_t)M_ * D_;            // M*E
  ushort* ub_bf   = y_bf + (size_t)M_ * E_;             // M*E
  ushort* g_bf    = ub_bf + (size_t)M_ * E_;            // M*E
  ushort* xdbc_bf = g_bf + (size_t)M_ * E_;             // M*64
  ushort* xwb     = xdbc_bf + (size_t)M_ * 64;          // NL*80*E
  ushort* dtwb    = xwb + (size_t)NL_ * XD_ * E_;       // NL*E*64
  ushort* in_wb   = dtwb + (size_t)NL_ * E_ * 64;       // NL*E2*D (norm_w folded)
  ushort* out_wb  = in_wb + (size_t)NL_ * E2_ * D_;     // NL*D*E

  // seed: zero ssq, then weight prep (+ norm_w fold) + input projection
  (void)hipMemsetAsync(ssq, 0, M_ * sizeof(float), stream);
  k_wprep<<<WB_ + 3 * M_, 256, 0, stream>>>(in_w, out_w, xproj_w, dt_w, norm_w,
                                            in_wb, out_wb, xwb, dtwb,
                                            x, proj_w, proj_b, h, hb_bf, ssq);

  for (int i = 0; i < NL_; i++) {
    // in-projection: A = h_bf, rmsnorm applied as epilogue row-scale (MODE 4)
    k_gemm_bf<128, 128, 4><<<dim3(E2_ / 128, M_ / 128), 256, 0, stream>>>(
        hb_bf, in_wb + (size_t)i * E2_ * D_, proj_bf, ssq, nullptr, nullptr, D_, E2_);
    k_conv2<<<M_ / TC_, 384, 0, stream>>>(proj_bf, conv_w + i * E_ * 4, conv_b + i * E_,
                                          ub_bf, g_bf);
    k_gemm_x<<<dim3(M_ / 64, KS_), 256, 0, stream>>>(ub_bf, xwb + (size_t)i * XD_ * E_, xpart);
    k_xfin<<<M_ * XD_ / 256, 256, 0, stream>>>(xpart, xdbc, xdbc_bf, ssq);
    k_scanA<<<dim3(E_ / 16, B_, NCH_), 256, 0, stream>>>(
        ub_bf, xdbc_bf, dtwb + (size_t)i * E_ * 64, dt_b + (size_t)i * E_, xdbc,
        A_log + (size_t)i * E_ * N_, Pst, Sst);
    k_scanC<<<dim3(E_ / 16, B_, NCH_), 256, 0, stream>>>(
        ub_bf, xdbc_bf, dtwb + (size_t)i * E_ * 64, dt_b + (size_t)i * E_, xdbc, g_bf,
        A_log + (size_t)i * E_ * N_, D_param + i * E_, Pst, Sst, y_bf);
    // out-projection: h += y@W^T, emit bf16 h + next-layer sumsq (MODE 5)
    k_gemm_bf<64, 64, 5><<<dim3(D_ / 64, M_ / 64), 256, 0, stream>>>(
        y_bf, out_wb + (size_t)i * D_ * E_, h, h, hb_bf, ssq, E_, D_);
  }

  k_pool<<<dim3(PC_, B_), 256, 0, stream>>>(h, pooledP);
  k_logits<<<1, 256, 0, stream>>>(pooledP, fnorm_w, cls_w, cls_b, out);
}

// Round 11
// 624.017 us; speedup vs baseline: 1.0384x; 1.0384x over previous
//
#include <hip/hip_runtime.h>

// Problem constants (match reference)
constexpr int B_  = 2;
constexpr int L_  = 1024;
constexpr int D_  = 768;
constexpr int E_  = 1536;
constexpr int N_  = 16;
constexpr int R_  = 48;
constexpr int NL_ = 4;
constexpr int NC_ = 5;
constexpr int M_  = B_ * L_;        // 2048 token rows
constexpr int E2_ = 2 * E_;         // 3072
constexpr int XD_ = R_ + 2 * N_;    // 80
constexpr float EPS_ = 1e-5f;
constexpr float LOG2E_ = 1.4426950408889634f;

constexpr int NCH_ = 16;            // time-chunks for parallel scan
constexpr int CL_  = L_ / NCH_;     // 64 timesteps per chunk
constexpr int KS_  = 8;             // split-K factor for xproj GEMM
constexpr int PC_  = 64;            // t-chunks for final pool (128 blocks)

typedef __attribute__((ext_vector_type(8))) short bf16x8;
typedef __attribute__((ext_vector_type(4))) float f32x4;
typedef const __attribute__((address_space(1))) void* gas_t;
typedef __attribute__((address_space(3))) void* las_t;

__device__ __forceinline__ float exp2fast(float x) { return __builtin_amdgcn_exp2f(x); }
__device__ __forceinline__ float sigm(float x) { return 1.0f / (1.0f + __expf(-x)); }
__device__ __forceinline__ float softplusf(float x) { return x > 20.0f ? x : log1pf(__expf(x)); }
__device__ __forceinline__ ushort f2b(float f) {  // fp32 -> bf16 RNE
  union { float f; unsigned u; } v; v.f = f;
  unsigned r = (v.u + 0x7fffu + ((v.u >> 16) & 1u)) >> 16;
  return (ushort)r;
}
__device__ __forceinline__ float b2f(ushort u) {
  union { unsigned u; float f; } v; v.u = ((unsigned)u) << 16;
  return v.f;
}
__device__ __forceinline__ float b2f_lo(unsigned p) {
  union { unsigned u; float f; } v; v.u = p << 16;
  return v.f;
}
__device__ __forceinline__ float b2f_hi(unsigned p) {
  union { unsigned u; float f; } v; v.u = p & 0xffff0000u;
  return v.f;
}

// DPP row_ror add: sum over 16-lane rows, full-rate VALU
template <int CTRL>
__device__ __forceinline__ float dpp_add(float x) {
  int yi = __builtin_amdgcn_update_dpp(0, __builtin_bit_cast(int, x), CTRL, 0xf, 0xf, false);
  return x + __builtin_bit_cast(float, yi);
}
__device__ __forceinline__ float row_sum16(float x) {
  x = dpp_add<0x121>(x);
  x = dpp_add<0x122>(x);
  x = dpp_add<0x124>(x);
  x = dpp_add<0x128>(x);
  return x;
}

__device__ __forceinline__ float block_sum(float v, float* sm) {
  #pragma unroll
  for (int o = 32; o > 0; o >>= 1) v += __shfl_xor(v, o);
  if ((threadIdx.x & 63) == 0) sm[threadIdx.x >> 6] = v;
  __syncthreads();
  return sm[0] + sm[1] + sm[2] + sm[3];
}

// One-shot prep: weight f2b conversions (in_w folded with norm_w, out_w, xproj_w;
// dt_w padded 48->64) PLUS the input projection h = x @ proj_w^T + proj_b.
// Input-proj: ONE block per token row (256 thr x 3 d) -> ssq[m] written directly
// (no memset, no atomics).
constexpr int WS1_ = NL_ * E2_ * D_;
constexpr int WS2_ = NL_ * D_ * E_;
constexpr int WS3_ = NL_ * XD_ * E_;
constexpr int WS4_ = NL_ * E_ * 64;
constexpr int WTOT_ = WS1_ + WS2_ + WS3_ + WS4_;
constexpr int WB_ = WTOT_ / 4 / 256;            // weight-conv blocks (exact: 14688)
__global__ __launch_bounds__(256) void k_wprep(const float* __restrict__ in_w, const float* __restrict__ out_w,
                                               const float* __restrict__ xw, const float* __restrict__ dw,
                                               const float* __restrict__ nw,
                                               ushort* __restrict__ in_wb, ushort* __restrict__ out_wb,
                                               ushort* __restrict__ xwb, ushort* __restrict__ dtwb,
                                               const float* __restrict__ x, const float* __restrict__ pw,
                                               const float* __restrict__ pb, float* __restrict__ h,
                                               ushort* __restrict__ hb, float* __restrict__ ssq) {
  if (blockIdx.x >= WB_) {
    // input projection: one block per token row
    __shared__ float xs[12];
    __shared__ float sm[4];
    int m = blockIdx.x - WB_;
    int tid = threadIdx.x;
    if (tid < 12) xs[tid] = x[m * 12 + tid];
    __syncthreads();
    float a[3];
    #pragma unroll
    for (int k2 = 0; k2 < 3; k2++) {
      int d = tid + k2 * 256;
      float acc = pb[d];
      #pragma unroll
      for (int j = 0; j < 12; j++) acc = fmaf(xs[j], pw[d * 12 + j], acc);
      h[(size_t)m * D_ + d] = acc;
      hb[(size_t)m * D_ + d] = f2b(acc);
      a[k2] = acc;
    }
    float s = block_sum(a[0] * a[0] + a[1] * a[1] + a[2] * a[2], sm);
    if (tid == 0) ssq[m] = s;
    return;
  }
  int i = (blockIdx.x * 256 + threadIdx.x) * 4;
  if (i < WS1_) {
    float4 v = *(const float4*)(in_w + i);
    int l = i / (E2_ * D_);
    int d = i % D_;                      // 4 consecutive d in the same row (D%4==0)
    float4 w = *(const float4*)(nw + l * D_ + d);
    *(ushort4*)(in_wb + i) = make_ushort4(f2b(v.x * w.x), f2b(v.y * w.y), f2b(v.z * w.z), f2b(v.w * w.w));
  } else if (i < WS1_ + WS2_) {
    int j = i - WS1_;
    float4 v = *(const float4*)(out_w + j);
    *(ushort4*)(out_wb + j) = make_ushort4(f2b(v.x), f2b(v.y), f2b(v.z), f2b(v.w));
  } else if (i < WS1_ + WS2_ + WS3_) {
    int j = i - WS1_ - WS2_;
    float4 v = *(const float4*)(xw + j);
    *(ushort4*)(xwb + j) = make_ushort4(f2b(v.x), f2b(v.y), f2b(v.z), f2b(v.w));
  } else {
    int j = i - WS1_ - WS2_ - WS3_;
    int k = j & 63, e = j >> 6;
    ushort4 o;
    o.x = (k + 0 < R_) ? f2b(dw[e * R_ + k + 0]) : (ushort)0;
    o.y = (k + 1 < R_) ? f2b(dw[e * R_ + k + 1]) : (ushort)0;
    o.z = (k + 2 < R_) ? f2b(dw[e * R_ + k + 2]) : (ushort)0;
    o.w = (k + 3 < R_) ? f2b(dw[e * R_ + k + 3]) : (ushort)0;
    *(ushort4*)(dtwb + j) = o;
  }
}

// C[M,Nd] = A_bf16[M,Kd] @ Bw_bf16[Nd,Kd]^T. MFMA 16x16x32 bf16.
// MODE 4: bf16 C=v*rsqrt(res[row]/D+eps)   (fused rmsnorm scale; res=ssq)
// MODE 5: fp32 C=v+res[off], also bf16 copy to Cb and atomic row-sumsq into ssq
template <int BM, int BN, int MODE>
__global__ __launch_bounds__(256) void k_gemm_bf(const ushort* __restrict__ A, const ushort* __restrict__ Bw,
                                                 void* __restrict__ Cv, const float* __restrict__ res,
                                                 ushort* __restrict__ Cb, float* __restrict__ ssq,
                                                 int Kd, int Nd) {
  constexpr int AM = BM / 32, BNF = BN / 32;
  __shared__ ushort sA[BM * 32];
  __shared__ ushort sB[BN * 32];
  const int tid = threadIdx.x;
  const int wave = tid >> 6, lane = tid & 63;
  const int q = lane >> 4, r = lane & 15;
  const int wm = wave >> 1, wn = wave & 1;
  const int m0 = blockIdx.y * BM, n0 = blockIdx.x * BN;
  f32x4 acc[AM][BNF] = {};

  for (int k0 = 0; k0 < Kd; k0 += 32) {
    #pragma unroll
    for (int j = 0; j < BM / 64; j++) {
      int i = j * 256 + tid;
      const ushort* gp = A + (size_t)(m0 + (i >> 2)) * Kd + k0 + ((i & 3) << 3);
      __builtin_amdgcn_global_load_lds((gas_t)gp, (las_t)(sA + ((j * 256 + wave * 64) << 3)), 16, 0, 0);
    }
    #pragma unroll
    for (int j = 0; j < BN / 64; j++) {
      int i = j * 256 + tid;
      const ushort* gp = Bw + (size_t)(n0 + (i >> 2)) * Kd + k0 + ((i & 3) << 3);
      __builtin_amdgcn_global_load_lds((gas_t)gp, (las_t)(sB + ((j * 256 + wave * 64) << 3)), 16, 0, 0);
    }
    __syncthreads();
    bf16x8 af[AM], bfv[BNF];
    #pragma unroll
    for (int mi = 0; mi < AM; mi++)
      af[mi] = *(const bf16x8*)&sA[(wm * (BM / 2) + mi * 16 + r) * 32 + q * 8];
    #pragma unroll
    for (int nj = 0; nj < BNF; nj++)
      bfv[nj] = *(const bf16x8*)&sB[(wn * (BN / 2) + nj * 16 + r) * 32 + q * 8];
    #pragma unroll
    for (int mi = 0; mi < AM; mi++)
      #pragma unroll
      for (int nj = 0; nj < BNF; nj++)
        acc[mi][nj] = __builtin_amdgcn_mfma_f32_16x16x32_bf16(af[mi], bfv[nj], acc[mi][nj], 0, 0, 0);
    __syncthreads();
  }
  // C/D layout: col = lane&15, row = (lane>>4)*4 + reg
  #pragma unroll
  for (int mi = 0; mi < AM; mi++) {
    #pragma unroll
    for (int rg = 0; rg < 4; rg++) {
      int row = m0 + wm * (BM / 2) + mi * 16 + q * 4 + rg;
      float rs = 0.0f, ssl = 0.0f;
      if (MODE == 4) rs = rsqrtf(res[row] * (1.0f / D_) + EPS_);
      #pragma unroll
      for (int nj = 0; nj < BNF; nj++) {
        int col = n0 + wn * (BN / 2) + nj * 16 + r;
        size_t off = (size_t)row * Nd + col;
        float v = acc[mi][nj][rg];
        if (MODE == 4) {
          ((ushort*)Cv)[off] = f2b(v * rs);
        } else if (MODE == 5) {
          v += res[off];
          ((float*)Cv)[off] = v;
          Cb[off] = f2b(v);
          ssl = fmaf(v, v, ssl);
        }
      }
      if (MODE == 5) {
        float sr = row_sum16(ssl);      // 16-lane group = fixed q = one row
        if (r == 0) atomicAdd(&ssq[row], sr);
      }
    }
  }
}

// xproj GEMM, split-K: part[ks][M][80] = u_bf[M, ks-slice] @ xwb[80, ks-slice]^T
__global__ __launch_bounds__(256) void k_gemm_x(const ushort* __restrict__ A, const ushort* __restrict__ Bw,
                                                float* __restrict__ part) {
  __shared__ ushort sA[64 * 32];
  __shared__ ushort sB[80 * 32];
  const int tid = threadIdx.x;
  const int wave = tid >> 6, lane = tid & 63;
  const int q = lane >> 4, r = lane & 15;
  const int m0 = blockIdx.x * 64;
  const int kbeg = blockIdx.y * (E_ / KS_), kend = kbeg + E_ / KS_;
  f32x4 acc[5] = {};

  for (int k0 = kbeg; k0 < kend; k0 += 32) {
    {
      const ushort* gp = A + (size_t)(m0 + wave * 16 + (lane >> 2)) * E_ + k0 + ((lane & 3) << 3);
      __builtin_amdgcn_global_load_lds((gas_t)gp, (las_t)(sA + (wave << 9)), 16, 0, 0);
    }
    #pragma unroll
    for (int j = wave; j < 5; j += 4) {
      const ushort* gp = Bw + (size_t)(j * 16 + (lane >> 2)) * E_ + k0 + ((lane & 3) << 3);
      __builtin_amdgcn_global_load_lds((gas_t)gp, (las_t)(sB + (j << 9)), 16, 0, 0);
    }
    __syncthreads();
    bf16x8 af = *(const bf16x8*)&sA[(wave * 16 + r) * 32 + q * 8];
    #pragma unroll
    for (int nj = 0; nj < 5; nj++) {
      bf16x8 bfv = *(const bf16x8*)&sB[(nj * 16 + r) * 32 + q * 8];
      acc[nj] = __builtin_amdgcn_mfma_f32_16x16x32_bf16(af, bfv, acc[nj], 0, 0, 0);
    }
    __syncthreads();
  }
  float* pp = part + (size_t)blockIdx.y * M_ * XD_;
  #pragma unroll
  for (int nj = 0; nj < 5; nj++) {
    int col = nj * 16 + r;
    #pragma unroll
    for (int rg = 0; rg < 4; rg++) {
      int row = m0 + wave * 16 + q * 4 + rg;
      pp[(size_t)row * XD_ + col] = acc[nj][rg];
    }
  }
}

// combine split-K partials -> xdbc fp32 [M][80] + bf16 dt-input copy [M][64]
// ALSO zeroes ssq[m] ahead of this layer's gemm_out MODE-5 accumulation.
__global__ __launch_bounds__(256) void k_xfin(const float* __restrict__ part, float* __restrict__ xdbc,
                                              ushort* __restrict__ xb, float* __restrict__ ssq) {
  int i = blockIdx.x * 256 + threadIdx.x;   // over M*80
  if (i < M_) ssq[i] = 0.0f;
  int m = i / XD_, col = i - m * XD_;
  float s = 0.0f;
  #pragma unroll
  for (int ks = 0; ks < KS_; ks++) s += part[(size_t)ks * M_ * XD_ + i];
  xdbc[i] = s;
  if (col < R_) xb[(size_t)m * 64 + col] = f2b(s);
  else if (col < 64) xb[(size_t)m * 64 + col] = 0;
}

// conv + silu for u; silu for gate. bf16 in (proj_bf), bf16 out.
constexpr int TC_ = 4;
__global__ __launch_bounds__(384) void k_conv2(const ushort* __restrict__ proj, const float* __restrict__ cw,
                                               const float* __restrict__ cb, ushort* __restrict__ ub16,
                                               ushort* __restrict__ gb16) {
  int m0 = blockIdx.x * TC_;          // TC_ | L_, so one batch per block
  int t0 = m0 & (L_ - 1);
  int base = m0 - t0;                 // b*L
  int e4 = threadIdx.x * 4;
  float wv[4][4];
  #pragma unroll
  for (int j = 0; j < 4; j++) {
    float4 w = *(const float4*)(cw + (e4 + j) * 4);
    wv[j][0] = w.x; wv[j][1] = w.y; wv[j][2] = w.z; wv[j][3] = w.w;
  }
  float4 bb = *(const float4*)(cb + e4);
  float bbv[4] = {bb.x, bb.y, bb.z, bb.w};
  float win[4][4];                    // win[0..2] = rows t-3..t-1; win[3] = current
  #pragma unroll
  for (int s = 0; s < 3; s++) {
    int t = t0 - 3 + s;
    if (t >= 0) {
      uint2 p = *(const uint2*)(proj + (size_t)(base + t) * E2_ + e4);
      win[s][0] = b2f_lo(p.x); win[s][1] = b2f_hi(p.x);
      win[s][2] = b2f_lo(p.y); win[s][3] = b2f_hi(p.y);
    } else {
      win[s][0] = win[s][1] = win[s][2] = win[s][3] = 0.0f;
    }
  }
  #pragma unroll
  for (int j = 0; j < TC_; j++) {
    size_t m = (size_t)(m0 + j);
    uint2 p = *(const uint2*)(proj + m * E2_ + e4);
    win[3][0] = b2f_lo(p.x); win[3][1] = b2f_hi(p.x);
    win[3][2] = b2f_lo(p.y); win[3][3] = b2f_hi(p.y);
    float o[4];
    #pragma unroll
    for (int c = 0; c < 4; c++) {
      float a = bbv[c];
      a = fmaf(wv[c][0], win[0][c], a);
      a = fmaf(wv[c][1], win[1][c], a);
      a = fmaf(wv[c][2], win[2][c], a);
      a = fmaf(wv[c][3], win[3][c], a);
      o[c] = a * sigm(a);
    }
    uint2 uo;
    uo.x = (unsigned)f2b(o[0]) | ((unsigned)f2b(o[1]) << 16);
    uo.y = (unsigned)f2b(o[2]) | ((unsigned)f2b(o[3]) << 16);
    *(uint2*)(ub16 + m * E_ + e4) = uo;
    #pragma unroll
    for (int s = 0; s < 3; s++) {
      win[s][0] = win[s + 1][0]; win[s][1] = win[s + 1][1];
      win[s][2] = win[s + 1][2]; win[s][3] = win[s + 1][3];
    }
  }
  // gate -> silu -> bf16 (no overlap; read once)
  #pragma unroll
  for (int j = 0; j < TC_; j++) {
    size_t m = (size_t)(m0 + j);
    uint2 g = *(const uint2*)(proj + m * E2_ + E_ + e4);
    float g0 = b2f_lo(g.x), g1 = b2f_hi(g.x), g2 = b2f_lo(g.y), g3 = b2f_hi(g.y);
    g0 *= sigm(g0); g1 *= sigm(g1); g2 *= sigm(g2); g3 *= sigm(g3);
    uint2 go;
    go.x = (unsigned)f2b(g0) | ((unsigned)f2b(g1) << 16);
    go.y = (unsigned)f2b(g2) | ((unsigned)f2b(g3) << 16);
    *(uint2*)(gb16 + m * E_ + e4) = go;
  }
}

// ---- Parallel (chunked) selective scan; dt via MFMA; slimmed VALU loop ------
// (round-9 proven versions: float2 (dt,dt*u) staging, exp2 folding, batched
//  y-finalize via lane capture)
__global__ __launch_bounds__(256, 6) void k_scanA(const ushort* __restrict__ u, const ushort* __restrict__ xb,
                                                  const ushort* __restrict__ dtw, const float* __restrict__ dtb_p,
                                                  const float* __restrict__ xdbc, const float* __restrict__ A_log,
                                                  float* __restrict__ Pst, float* __restrict__ Sst) {
  __shared__ float2 s_dd[CL_][16];   // (dt, dt*u) 8 KB
  __shared__ float  s_b [CL_][16];   // 4 KB
  const int tid = threadIdx.x;
  const int e0 = blockIdx.x << 4;
  const int b  = blockIdx.y;
  const int c  = blockIdx.z;
  const int n  = tid & 15, el = tid >> 4;
  const int e  = e0 + el;
  const int wave = tid >> 6, lane = tid & 63;
  const int q = lane >> 4, r = lane & 15;
  const float A2 = -__expf(A_log[e * N_ + n]) * LOG2E_;
  const int mb = b * L_ + c * CL_;

  // dt tile via MFMA: wave w owns t-range [w*16, w*16+16)
  f32x4 dacc = {};
  #pragma unroll
  for (int k0 = 0; k0 < 64; k0 += 32) {
    bf16x8 af = *(const bf16x8*)&xb[(size_t)(mb + wave * 16 + r) * 64 + k0 + q * 8];
    bf16x8 bfv = *(const bf16x8*)&dtw[(e0 + r) * 64 + k0 + q * 8];
    dacc = __builtin_amdgcn_mfma_f32_16x16x32_bf16(af, bfv, dacc, 0, 0, 0);
  }
  {
    float db = dtb_p[e0 + r];
    #pragma unroll
    for (int rg = 0; rg < 4; rg++)
      s_dd[wave * 16 + q * 4 + rg][r].x = softplusf(dacc[rg] + db);
  }

  ushort r_u[4];
  #pragma unroll
  for (int j = 0; j < 4; j++) {
    r_u[j] = u[(size_t)(mb + j * 16 + el) * E_ + e0 + n];
    int idx = j * 256 + tid;
    s_b[idx >> 4][idx & 15] = xdbc[(size_t)(mb + (idx >> 4)) * XD_ + R_ + (idx & 15)];
  }
  __syncthreads();
  // dtu pass: s_dd[t][c].y = dt * u (per thread: 4 pairs)
  #pragma unroll
  for (int j = 0; j < 4; j++) {
    int t = j * 16 + el;
    s_dd[t][n].y = s_dd[t][n].x * b2f(r_u[j]);
  }
  __syncthreads();

  float hs = 0.0f, sdt = 0.0f;
  #pragma unroll 8
  for (int t = 0; t < CL_; t++) {
    float2 dd = s_dd[t][el];
    float dA = exp2fast(dd.x * A2);
    hs = fmaf(hs, dA, dd.y * s_b[t][n]);
    sdt += dd.x;
  }
  size_t o = (((size_t)(b * NCH_ + c) * E_) + e) * N_ + n;
  Pst[o] = exp2fast(A2 * sdt);
  Sst[o] = hs;
}

// scanC: slim loop + batched y-finalize. After row_sum16 ALL 16 lanes hold the
// row sum; lane n captures the sum at t==base+n (cmp+cndmask), and every 16 t a
// single all-lane flush does the y math (replaces the per-t exec-masked tail).
__global__ __launch_bounds__(256, 6) void k_scanC(const ushort* __restrict__ u, const ushort* __restrict__ xb,
                                                  const ushort* __restrict__ dtw, const float* __restrict__ dtb_p,
                                                  const float* __restrict__ xdbc, const ushort* __restrict__ gb,
                                                  const float* __restrict__ A_log, const float* __restrict__ Dp,
                                                  const float* __restrict__ Pst, const float* __restrict__ Sst,
                                                  ushort* __restrict__ y) {
  __shared__ float2 s_dd[CL_][16];   // (dt, dt*u) 8 KB
  __shared__ float2 s_bc[CL_][16];   // 8 KB
  __shared__ uint   s_ug[CL_][16];   // 4 KB: u | g<<16 (bf16 raw bits)
  __shared__ ushort s_y [CL_][16];   // 2 KB   -> 22.5 KB total
  const int tid = threadIdx.x;
  const int e0 = blockIdx.x << 4;
  const int b  = blockIdx.y;
  const int c  = blockIdx.z;
  const int n  = tid & 15, el = tid >> 4;
  const int e  = e0 + el;
  const int wave = tid >> 6, lane = tid & 63;
  const int q = lane >> 4, r = lane & 15;
  const float A2 = -__expf(A_log[e * N_ + n]) * LOG2E_;
  const float Dv = Dp[e];
  const int t0 = c * CL_;
  const int mb = b * L_ + t0;

  // dt tile via MFMA (identical to k_scanA)
  f32x4 dacc = {};
  #pragma unroll
  for (int k0 = 0; k0 < 64; k0 += 32) {
    bf16x8 af = *(const bf16x8*)&xb[(size_t)(mb + wave * 16 + r) * 64 + k0 + q * 8];
    bf16x8 bfv = *(const bf16x8*)&dtw[(e0 + r) * 64 + k0 + q * 8];
    dacc = __builtin_amdgcn_mfma_f32_16x16x32_bf16(af, bfv, dacc, 0, 0, 0);
  }
  {
    float db = dtb_p[e0 + r];
    #pragma unroll
    for (int rg = 0; rg < 4; rg++)
      s_dd[wave * 16 + q * 4 + rg][r].x = softplusf(dacc[rg] + db);
  }

  ushort r_u[4], r_g[4];
  float r_bc[8];
  #pragma unroll
  for (int j = 0; j < 4; j++) {
    size_t m = (size_t)(mb + j * 16 + el);
    r_u[j] = u[m * E_ + e0 + n];
    r_g[j] = gb[m * E_ + e0 + n];
  }
  #pragma unroll
  for (int j = 0; j < 8; j++) {
    int idx = j * 256 + tid;
    r_bc[j] = xdbc[(size_t)(mb + (idx >> 5)) * XD_ + R_ + (idx & 31)];
  }

  // branchless parallel lookback over predecessor chunk summaries
  float hs = 0.0f;
  if (c > 0) {
    float pv[NCH_ - 1], sv[NCH_ - 1];
    #pragma unroll
    for (int cc = 0; cc < NCH_ - 1; cc++) {
      int ci = cc < c ? cc : c - 1;
      size_t o = (((size_t)(b * NCH_ + ci) * E_) + e) * N_ + n;
      pv[cc] = Pst[o];
      sv[cc] = Sst[o];
    }
    #pragma unroll
    for (int cc = 0; cc < NCH_ - 1; cc++) {
      bool v = cc < c;
      hs = fmaf(v ? pv[cc] : 1.0f, hs, v ? sv[cc] : 0.0f);
    }
  }

  #pragma unroll
  for (int j = 0; j < 4; j++) {
    int t = j * 16 + el;
    s_ug[t][n] = (uint)r_u[j] | ((uint)r_g[j] << 16);
  }
  #pragma unroll
  for (int j = 0; j < 8; j++) {
    int idx = j * 256 + tid;
    int t = idx >> 5, col = idx & 31;
    ((float*)&s_bc[t][0])[((col & 15) << 1) + (col >> 4)] = r_bc[j];
  }
  __syncthreads();
  // dtu pass
  #pragma unroll
  for (int j = 0; j < 4; j++) {
    int t = j * 16 + el;
    s_dd[t][n].y = s_dd[t][n].x * b2f(r_u[j]);
  }
  __syncthreads();

  for (int base = 0; base < CL_; base += 16) {
    float pslot = 0.0f;
    #pragma unroll
    for (int tt = 0; tt < 16; tt++) {
      int t = base + tt;
      float2 dd = s_dd[t][el];
      float2 bc = s_bc[t][n];
      float dA = exp2fast(dd.x * A2);
      hs = fmaf(hs, dA, dd.y * bc.x);
      float p = row_sum16(hs * bc.y);
      pslot = (n == tt) ? p : pslot;      // lane n captures t = base+n
    }
    // all-lane flush: lane n finalizes y at t = base+n
    uint ug = s_ug[base + n][el];
    s_y[base + n][el] = f2b((pslot + b2f_lo(ug) * Dv) * b2f_hi(ug));
  }
  __syncthreads();

  {
    int row = tid >> 2, seg = tid & 3;
    uint2 v = *(const uint2*)&s_y[row][seg * 4];
    *(uint2*)(y + (size_t)(mb + row) * E_ + e0 + seg * 4) = v;
  }
}

// Fused rowscale+pool+logits: block (pc,b) reads its 16 rows ONCE; per row
// block-reduce sumsq -> rs; accumulate pooled partial in registers; then fold
// fnorm_w/L and compute the 5-class partial dot, atomicAdd into out (zeroed by
// harness). cb added by the pc==0 block. No pooledP buffer, no logits kernel.
__global__ __launch_bounds__(256) void k_pool(const float* __restrict__ h, const float* __restrict__ fw,
                                              const float* __restrict__ cw, const float* __restrict__ cb,
                                              float* __restrict__ out) {
  __shared__ float sm[4];
  const int pc = blockIdx.x, b = blockIdx.y;
  const int tid = threadIdx.x;
  const int t0 = pc * (L_ / PC_);
  float a0 = 0.0f, a1 = 0.0f, a2 = 0.0f;
  for (int rowi = 0; rowi < L_ / PC_; rowi++) {
    const float* hr = h + (size_t)(b * L_ + t0 + rowi) * D_;
    float v0 = hr[tid], v1 = hr[tid + 256], v2 = hr[tid + 512];
    float s = block_sum(v0 * v0 + v1 * v1 + v2 * v2, sm);
    float rs = rsqrtf(s * (1.0f / D_) + EPS_);
    a0 = fmaf(v0, rs, a0); a1 = fmaf(v1, rs, a1); a2 = fmaf(v2, rs, a2);
    __syncthreads();   // guard sm reuse next row
  }
  const float inv = 1.0f / (float)L_;
  a0 *= fw[tid] * inv;
  a1 *= fw[tid + 256] * inv;
  a2 *= fw[tid + 512] * inv;
  #pragma unroll
  for (int c = 0; c < NC_; c++) {
    float s = a0 * cw[c * D_ + tid] + a1 * cw[c * D_ + tid + 256] + a2 * cw[c * D_ + tid + 512];
    s = block_sum(s, sm);
    if (tid == 0) {
      float add = (pc == 0) ? cb[c] : 0.0f;
      atomicAdd(&out[b * NC_ + c], s + add);
    }
    __syncthreads();   // guard sm reuse next class
  }
}

extern "C" void kernel_launch(void* const* d_in, const int* in_sizes, int n_in,
                              void* d_out, int out_size, void* d_ws, size_t ws_size,
                              hipStream_t stream) {
  const float* x       = (const float*)d_in[0];
  const float* proj_w  = (const float*)d_in[1];
  const float* proj_b  = (const float*)d_in[2];
  const float* norm_w  = (const float*)d_in[3];
  const float* in_w    = (const float*)d_in[4];
  const float* conv_w  = (const float*)d_in[5];
  const float* conv_b  = (const float*)d_in[6];
  const float* xproj_w = (const float*)d_in[7];
  const float* dt_w    = (const float*)d_in[8];
  const float* dt_b    = (const float*)d_in[9];
  const float* A_log   = (const float*)d_in[10];
  const float* D_param = (const float*)d_in[11];
  const float* out_w   = (const float*)d_in[12];
  const float* fnorm_w = (const float*)d_in[13];
  const float* cls_w   = (const float*)d_in[14];
  const float* cls_b   = (const float*)d_in[15];
  float* out = (float*)d_out;

  // workspace layout (floats)
  float* h      = (float*)d_ws;                         // M*D
  float* xdbc   = h + (size_t)M_ * D_;                  // M*80
  float* ssq    = xdbc + (size_t)M_ * XD_;              // M (running row sumsq)
  float* Pst    = ssq + M_;                             // B*NCH*E*N
  float* Sst    = Pst + (size_t)B_ * NCH_ * E_ * N_;    // B*NCH*E*N
  float* xpart  = Sst + (size_t)B_ * NCH_ * E_ * N_;    // KS*M*80
  ushort* proj_bf = (ushort*)(xpart + (size_t)KS_ * M_ * XD_);  // M*2E bf16
  ushort* hb_bf   = proj_bf + (size_t)M_ * E2_;         // M*D (bf16 of residual h)
  ushort* y_bf    = hb_bf + (size_t)M_ * D_;            // M*E
  ushort* ub_bf   = y_bf + (size_t)M_ * E_;             // M*E
  ushort* g_bf    = ub_bf + (size_t)M_ * E_;            // M*E
  ushort* xdbc_bf = g_bf + (size_t)M_ * E_;             // M*64
  ushort* xwb     = xdbc_bf + (size_t)M_ * 64;          // NL*80*E
  ushort* dtwb    = xwb + (size_t)NL_ * XD_ * E_;       // NL*E*64
  ushort* in_wb   = dtwb + (size_t)NL_ * E_ * 64;       // NL*E2*D (norm_w folded)
  ushort* out_wb  = in_wb + (size_t)NL_ * E2_ * D_;     // NL*D*E

  // weight prep (+ norm_w fold) + input projection (1 block/row, direct ssq)
  k_wprep<<<WB_ + M_, 256, 0, stream>>>(in_w, out_w, xproj_w, dt_w, norm_w,
                                        in_wb, out_wb, xwb, dtwb,
                                        x, proj_w, proj_b, h, hb_bf, ssq);

  for (int i = 0; i < NL_; i++) {
    // in-projection: A = h_bf, rmsnorm applied as epilogue row-scale (MODE 4)
    k_gemm_bf<128, 128, 4><<<dim3(E2_ / 128, M_ / 128), 256, 0, stream>>>(
        hb_bf, in_wb + (size_t)i * E2_ * D_, proj_bf, ssq, nullptr, nullptr, D_, E2_);
    k_conv2<<<M_ / TC_, 384, 0, stream>>>(proj_bf, conv_w + i * E_ * 4, conv_b + i * E_,
                                          ub_bf, g_bf);
    k_gemm_x<<<dim3(M_ / 64, KS_), 256, 0, stream>>>(ub_bf, xwb + (size_t)i * XD_ * E_, xpart);
    k_xfin<<<M_ * XD_ / 256, 256, 0, stream>>>(xpart, xdbc, xdbc_bf, ssq);
    k_scanA<<<dim3(E_ / 16, B_, NCH_), 256, 0, stream>>>(
        ub_bf, xdbc_bf, dtwb + (size_t)i * E_ * 64, dt_b + (size_t)i * E_, xdbc,
        A_log + (size_t)i * E_ * N_, Pst, Sst);
    k_scanC<<<dim3(E_ / 16, B_, NCH_), 256, 0, stream>>>(
        ub_bf, xdbc_bf, dtwb + (size_t)i * E_ * 64, dt_b + (size_t)i * E_, xdbc, g_bf,
        A_log + (size_t)i * E_ * N_, D_param + i * E_, Pst, Sst, y_bf);
    // out-projection: h += y@W^T, emit bf16 h + next-layer sumsq (MODE 5)
    k_gemm_bf<64, 64, 5><<<dim3(D_ / 64, M_ / 64), 256, 0, stream>>>(
        y_bf, out_wb + (size_t)i * D_ * E_, h, h, hb_bf, ssq, E_, D_);
  }

  k_pool<<<dim3(PC_, B_), 256, 0, stream>>>(h, fnorm_w, cls_w, cls_b, out);
}